// Round 1
// baseline (1344.758 us; speedup 1.0000x reference)
//
#include <hip/hip_runtime.h>
#include <hip/hip_bf16.h>
#include <math.h>

#define BATCH 2
#define SEQ   2048
#define DMODEL 768
#define DIN   384
#define DINNER 768
#define DSTATE 16
#define DTRANK 24
#define ROWS  (BATCH*SEQ)   // 4096

// ---------------------------------------------------------------------------
// LayerNorm (optionally with residual add). One block per row of 768.
// ---------------------------------------------------------------------------
__global__ __launch_bounds__(256) void ln_kernel(
    const float* __restrict__ x, const float* __restrict__ res,
    const float* __restrict__ w, const float* __restrict__ b,
    float* __restrict__ out)
{
    int row = blockIdx.x;
    int tid = threadIdx.x;
    const float* xr = x + (size_t)row * DMODEL;
    const float* rr = res ? res + (size_t)row * DMODEL : nullptr;
    float v[3];
    float s = 0.f, sq = 0.f;
#pragma unroll
    for (int j = 0; j < 3; j++) {
        int i = tid + j * 256;
        float val = xr[i];
        if (rr) val += rr[i];
        v[j] = val; s += val; sq += val * val;
    }
#pragma unroll
    for (int off = 32; off; off >>= 1) {
        s  += __shfl_down(s,  off);
        sq += __shfl_down(sq, off);
    }
    __shared__ float ss[4], ssq[4];
    __shared__ float mean_s, rstd_s;
    int wid = tid >> 6;
    if ((tid & 63) == 0) { ss[wid] = s; ssq[wid] = sq; }
    __syncthreads();
    if (tid == 0) {
        float S  = ss[0] + ss[1] + ss[2] + ss[3];
        float SQ = ssq[0] + ssq[1] + ssq[2] + ssq[3];
        float m  = S * (1.0f / DMODEL);
        float var = SQ * (1.0f / DMODEL) - m * m;
        mean_s = m;
        rstd_s = rsqrtf(var + 1e-5f);
    }
    __syncthreads();
    float m = mean_s, rs = rstd_s;
    float* orow = out + (size_t)row * DMODEL;
#pragma unroll
    for (int j = 0; j < 3; j++) {
        int i = tid + j * 256;
        orow[i] = (v[j] - m) * rs * w[i] + b[i];
    }
}

// ---------------------------------------------------------------------------
// Generic fp32 GEMM: C[M,N] = A[M,K] @ W[K,N] (+ bias) (+ softplus if act==1)
// 64x64 tile per 256-thread block, 4x4 per thread, BK=16.
// ---------------------------------------------------------------------------
#define BM 64
#define BN 64
#define BK 16
__global__ __launch_bounds__(256) void gemm_kernel(
    const float* __restrict__ A, int lda,
    const float* __restrict__ W, int ldw,
    const float* __restrict__ bias,
    float* __restrict__ C, int ldc,
    int M, int N, int K, int act)
{
    __shared__ float As[BK][BM + 4];
    __shared__ float Bs[BK][BN + 4];
    int tid = threadIdx.x;
    int m0 = blockIdx.y * BM;
    int n0 = blockIdx.x * BN;
    int tx = tid & 15, ty = tid >> 4;
    float acc[4][4] = {};

    for (int k0 = 0; k0 < K; k0 += BK) {
        // --- A tile: 64 rows x 16 k (M=4096 -> rows always in-bounds)
        {
            int row = tid >> 2;
            int kq  = (tid & 3) * 4;
            const float* ap = A + (size_t)(m0 + row) * lda + k0 + kq;
            float4 av;
            if (k0 + BK <= K) {
                av = *(const float4*)ap;
            } else {
                float t0 = (k0 + kq + 0 < K) ? ap[0] : 0.f;
                float t1 = (k0 + kq + 1 < K) ? ap[1] : 0.f;
                float t2 = (k0 + kq + 2 < K) ? ap[2] : 0.f;
                float t3 = (k0 + kq + 3 < K) ? ap[3] : 0.f;
                av = make_float4(t0, t1, t2, t3);
            }
            As[kq + 0][row] = av.x;
            As[kq + 1][row] = av.y;
            As[kq + 2][row] = av.z;
            As[kq + 3][row] = av.w;
        }
        // --- B tile: 16 k x 64 n
        {
            int krow = tid >> 4;
            int col  = (tid & 15) * 4;
            float4 wv = make_float4(0.f, 0.f, 0.f, 0.f);
            if (k0 + krow < K) {
                const float* wp = W + (size_t)(k0 + krow) * ldw + n0 + col;
                if (n0 + col + 3 < N) {
                    wv = *(const float4*)wp;
                } else {
                    float t0 = (n0 + col + 0 < N) ? wp[0] : 0.f;
                    float t1 = (n0 + col + 1 < N) ? wp[1] : 0.f;
                    float t2 = (n0 + col + 2 < N) ? wp[2] : 0.f;
                    float t3 = (n0 + col + 3 < N) ? wp[3] : 0.f;
                    wv = make_float4(t0, t1, t2, t3);
                }
            }
            *(float4*)&Bs[krow][col] = wv;
        }
        __syncthreads();
#pragma unroll
        for (int k = 0; k < BK; k++) {
            float a[4], bv[4];
            *(float4*)a  = *(const float4*)&As[k][ty * 4];
            *(float4*)bv = *(const float4*)&Bs[k][tx * 4];
#pragma unroll
            for (int i = 0; i < 4; i++)
#pragma unroll
                for (int j = 0; j < 4; j++)
                    acc[i][j] = fmaf(a[i], bv[j], acc[i][j]);
        }
        __syncthreads();
    }
#pragma unroll
    for (int i = 0; i < 4; i++) {
        int m = m0 + ty * 4 + i;
#pragma unroll
        for (int j = 0; j < 4; j++) {
            int n = n0 + tx * 4 + j;
            if (n < N) {
                float v = acc[i][j] + (bias ? bias[n] : 0.f);
                if (act == 1) v = (v > 20.f) ? v : log1pf(__expf(v));
                C[(size_t)m * ldc + n] = v;
            }
        }
    }
}

// ---------------------------------------------------------------------------
// Causal conv1d (K=4) + SiLU. rev==1 runs anticausal (backward direction, time
// flip folded into conv instead of materializing flipped tensors).
// Input = x-half of xz (row stride 1536).
// ---------------------------------------------------------------------------
__global__ __launch_bounds__(256) void conv_silu_kernel(
    const float* __restrict__ xz,
    const float* __restrict__ cw, const float* __restrict__ cb,
    float* __restrict__ out, int rev)
{
    int idx = blockIdx.x * 256 + threadIdx.x;
    if (idx >= ROWS * DINNER) return;
    int d = idx % DINNER;
    int row = idx / DINNER;
    int t = row & (SEQ - 1);
    int b = row >> 11;
    float acc = cb[d];
#pragma unroll
    for (int k = 0; k < 4; k++) {
        int ts = rev ? (t + 3 - k) : (t - 3 + k);
        if (ts >= 0 && ts < SEQ)
            acc = fmaf(cw[d * 4 + k], xz[((size_t)(b * SEQ + ts)) * 1536 + d], acc);
    }
    float sig = 1.f / (1.f + __expf(-acc));
    out[idx] = acc * sig;
}

// ---------------------------------------------------------------------------
// Selective scan. Block = 16 channels x 16 states (256 thr). One block scans
// the whole sequence for (dir, batch, 16-channel group). 64-step LDS tiles.
// Fused epilogue: y = (scan_y + x*D) * silu(z).
// ---------------------------------------------------------------------------
__global__ __launch_bounds__(256) void scan_kernel(
    const float* __restrict__ dtf, const float* __restrict__ xcf,
    const float* __restrict__ xdf, const float* __restrict__ xzf,
    const float* __restrict__ Alf, const float* __restrict__ Dff,
    const float* __restrict__ dtb, const float* __restrict__ xcb,
    const float* __restrict__ xdb, const float* __restrict__ xzb,
    const float* __restrict__ Alb, const float* __restrict__ Dbb,
    float* __restrict__ yf, float* __restrict__ yb)
{
    int chgrp = blockIdx.x;   // 0..47
    int bat   = blockIdx.y;   // 0..1
    int dir   = blockIdx.z;   // 0..1

    const float* dt = dir ? dtb : dtf;
    const float* xc = dir ? xcb : xcf;
    const float* xd = dir ? xdb : xdf;
    const float* xz = dir ? xzb : xzf;
    const float* Al = dir ? Alb : Alf;
    const float* Dp = dir ? Dbb : Dff;
    float* yo = dir ? yb : yf;

    int tid = threadIdx.x;
    int n = tid & 15;
    int c = tid >> 4;
    int d = chgrp * 16 + c;

    float a  = -__expf(Al[d * DSTATE + n]);
    float Dd = Dp[d];
    float h = 0.f;

    __shared__ float sdt[64][16], sx[64][16], sB[64][16], sC[64][16], sz[64][16];

    for (int tile = 0; tile < SEQ / 64; tile++) {
        int s0 = tile * 64;
        for (int idx = tid; idx < 64 * 16; idx += 256) {
            int tl = idx >> 4, cc = idx & 15;
            int s = s0 + tl;
            int t = dir ? (SEQ - 1 - s) : s;
            size_t rrow = (size_t)(bat * SEQ + t);
            sdt[tl][cc] = dt[rrow * DINNER + chgrp * 16 + cc];
            sx [tl][cc] = xc[rrow * DINNER + chgrp * 16 + cc];
            sz [tl][cc] = xz[rrow * 1536 + DINNER + chgrp * 16 + cc];
            sB [tl][cc] = xd[rrow * 56 + DTRANK + cc];
            sC [tl][cc] = xd[rrow * 56 + DTRANK + DSTATE + cc];
        }
        __syncthreads();
#pragma unroll 4
        for (int i = 0; i < 64; i++) {
            float dtv = sdt[i][c];
            float xv  = sx[i][c];
            float w = __expf(dtv * a);
            h = fmaf(w, h, dtv * xv * sB[i][n]);
            float yc = h * sC[i][n];
            yc += __shfl_xor(yc, 1);
            yc += __shfl_xor(yc, 2);
            yc += __shfl_xor(yc, 4);
            yc += __shfl_xor(yc, 8);
            if (n == 0) {
                int s = s0 + i;
                int t = dir ? (SEQ - 1 - s) : s;
                float zv = sz[i][c];
                float sig = 1.f / (1.f + __expf(-zv));
                yo[((size_t)(bat * SEQ + t)) * DINNER + d] = (yc + xv * Dd) * (zv * sig);
            }
        }
        __syncthreads();
    }
}

// ---------------------------------------------------------------------------
extern "C" void kernel_launch(void* const* d_in, const int* in_sizes, int n_in,
                              void* d_out, int out_size, void* d_ws, size_t ws_size,
                              hipStream_t stream)
{
    const float* x        = (const float*)d_in[0];
    const float* in_nw    = (const float*)d_in[1];
    const float* in_nb    = (const float*)d_in[2];
    const float* ip_w     = (const float*)d_in[3];
    const float* ip_b     = (const float*)d_in[4];
    const float* f_in_w   = (const float*)d_in[5];
    const float* f_in_b   = (const float*)d_in[6];
    const float* f_conv_w = (const float*)d_in[7];
    const float* f_conv_b = (const float*)d_in[8];
    const float* f_xp_w   = (const float*)d_in[9];
    const float* f_dt_w   = (const float*)d_in[10];
    const float* f_dt_b   = (const float*)d_in[11];
    const float* f_A_log  = (const float*)d_in[12];
    const float* f_D      = (const float*)d_in[13];
    const float* f_out_w  = (const float*)d_in[14];
    const float* f_out_b  = (const float*)d_in[15];
    const float* b_in_w   = (const float*)d_in[16];
    const float* b_in_b   = (const float*)d_in[17];
    const float* b_conv_w = (const float*)d_in[18];
    const float* b_conv_b = (const float*)d_in[19];
    const float* b_xp_w   = (const float*)d_in[20];
    const float* b_dt_w   = (const float*)d_in[21];
    const float* b_dt_b   = (const float*)d_in[22];
    const float* b_A_log  = (const float*)d_in[23];
    const float* b_D      = (const float*)d_in[24];
    const float* b_out_w  = (const float*)d_in[25];
    const float* b_out_b  = (const float*)d_in[26];
    const float* op_w     = (const float*)d_in[27];
    const float* op_b     = (const float*)d_in[28];
    const float* norm_w   = (const float*)d_in[29];
    const float* norm_b   = (const float*)d_in[30];

    float* ws = (float*)d_ws;
    const size_t R = ROWS;
    float* xn   = ws;                       // R*768
    float* xp   = xn   + R * 768;           // R*768
    float* xz_f = xp   + R * 768;           // R*1536
    float* xz_b = xz_f + R * 1536;          // R*1536
    float* xc_f = xz_b + R * 1536;          // R*768
    float* xc_b = xc_f + R * 768;           // R*768
    float* xd_f = xc_b + R * 768;           // R*56
    float* xd_b = xd_f + R * 56;            // R*56
    float* dt_f = xd_b + R * 56;            // R*768
    float* dt_b = dt_f + R * 768;           // R*768
    float* y_f  = dt_b + R * 768;           // R*768
    float* y_b  = y_f  + R * 768;           // R*768
    float* cat    = xp;   // reuse: xp dead after xz GEMMs
    float* outraw = xn;   // reuse: xn dead after xp GEMM

    dim3 blk(256);

    // 1. input layernorm
    hipLaunchKernelGGL(ln_kernel, dim3(ROWS), blk, 0, stream, x, nullptr, in_nw, in_nb, xn);
    // 2. xp = xn @ ip_w + ip_b
    hipLaunchKernelGGL(gemm_kernel, dim3(768 / BN, ROWS / BM), blk, 0, stream,
                       xn, 768, ip_w, 768, ip_b, xp, 768, ROWS, 768, 768, 0);
    // 3/4. xz = split(xp) @ {f,b}_in_w + bias
    hipLaunchKernelGGL(gemm_kernel, dim3(1536 / BN, ROWS / BM), blk, 0, stream,
                       xp, 768, f_in_w, 1536, f_in_b, xz_f, 1536, ROWS, 1536, DIN, 0);
    hipLaunchKernelGGL(gemm_kernel, dim3(1536 / BN, ROWS / BM), blk, 0, stream,
                       xp + DIN, 768, b_in_w, 1536, b_in_b, xz_b, 1536, ROWS, 1536, DIN, 0);
    // 5. conv + silu (direction-aware)
    hipLaunchKernelGGL(conv_silu_kernel, dim3(ROWS * DINNER / 256), blk, 0, stream,
                       xz_f, f_conv_w, f_conv_b, xc_f, 0);
    hipLaunchKernelGGL(conv_silu_kernel, dim3(ROWS * DINNER / 256), blk, 0, stream,
                       xz_b, b_conv_w, b_conv_b, xc_b, 1);
    // 6/7. xd = xc @ xp_w  (N=56)
    hipLaunchKernelGGL(gemm_kernel, dim3(1, ROWS / BM), blk, 0, stream,
                       xc_f, 768, f_xp_w, 56, nullptr, xd_f, 56, ROWS, 56, 768, 0);
    hipLaunchKernelGGL(gemm_kernel, dim3(1, ROWS / BM), blk, 0, stream,
                       xc_b, 768, b_xp_w, 56, nullptr, xd_b, 56, ROWS, 56, 768, 0);
    // 8/9. dt = softplus(xd[:, :24] @ dt_w + dt_b)
    hipLaunchKernelGGL(gemm_kernel, dim3(768 / BN, ROWS / BM), blk, 0, stream,
                       xd_f, 56, f_dt_w, 768, f_dt_b, dt_f, 768, ROWS, 768, DTRANK, 1);
    hipLaunchKernelGGL(gemm_kernel, dim3(768 / BN, ROWS / BM), blk, 0, stream,
                       xd_b, 56, b_dt_w, 768, b_dt_b, dt_b, 768, ROWS, 768, DTRANK, 1);
    // 10. selective scan, both dirs, fused (+x*D)*silu(z)
    hipLaunchKernelGGL(scan_kernel, dim3(DINNER / 16, BATCH, 2), blk, 0, stream,
                       dt_f, xc_f, xd_f, xz_f, f_A_log, f_D,
                       dt_b, xc_b, xd_b, xz_b, b_A_log, b_D,
                       y_f, y_b);
    // 11/12. out_{f,b} = y @ out_w + out_b -> concat buffer columns
    hipLaunchKernelGGL(gemm_kernel, dim3(DIN / BN, ROWS / BM), blk, 0, stream,
                       y_f, 768, f_out_w, 384, f_out_b, cat, 768, ROWS, 384, 768, 0);
    hipLaunchKernelGGL(gemm_kernel, dim3(DIN / BN, ROWS / BM), blk, 0, stream,
                       y_b, 768, b_out_w, 384, b_out_b, cat + DIN, 768, ROWS, 384, 768, 0);
    // 13. op projection
    hipLaunchKernelGGL(gemm_kernel, dim3(768 / BN, ROWS / BM), blk, 0, stream,
                       cat, 768, op_w, 768, op_b, outraw, 768, ROWS, 768, 768, 0);
    // 14. final layernorm(residual + out)
    hipLaunchKernelGGL(ln_kernel, dim3(ROWS), blk, 0, stream,
                       x, outraw, norm_w, norm_b, (float*)d_out);
}

// Round 2
// 816.564 us; speedup vs baseline: 1.6468x; 1.6468x over previous
//
#include <hip/hip_runtime.h>
#include <hip/hip_bf16.h>
#include <math.h>
#include <type_traits>

#define BATCH 2
#define SEQ   2048
#define DMODEL 768
#define DIN   384
#define DINNER 768
#define DSTATE 16
#define DTRANK 24
#define ROWS  (BATCH*SEQ)   // 4096
#define NCH   32            // time chunks for the scan
#define CLEN  (SEQ/NCH)     // 64 steps per chunk

// ---------------------------------------------------------------------------
// LayerNorm (optionally with residual add). One block per row of 768.
// ---------------------------------------------------------------------------
__global__ __launch_bounds__(256) void ln_kernel(
    const float* __restrict__ x, const float* __restrict__ res,
    const float* __restrict__ w, const float* __restrict__ b,
    float* __restrict__ out)
{
    int row = blockIdx.x;
    int tid = threadIdx.x;
    const float* xr = x + (size_t)row * DMODEL;
    const float* rr = res ? res + (size_t)row * DMODEL : nullptr;
    float v[3];
    float s = 0.f, sq = 0.f;
#pragma unroll
    for (int j = 0; j < 3; j++) {
        int i = tid + j * 256;
        float val = xr[i];
        if (rr) val += rr[i];
        v[j] = val; s += val; sq += val * val;
    }
#pragma unroll
    for (int off = 32; off; off >>= 1) {
        s  += __shfl_down(s,  off);
        sq += __shfl_down(sq, off);
    }
    __shared__ float ss[4], ssq[4];
    __shared__ float mean_s, rstd_s;
    int wid = tid >> 6;
    if ((tid & 63) == 0) { ss[wid] = s; ssq[wid] = sq; }
    __syncthreads();
    if (tid == 0) {
        float S  = ss[0] + ss[1] + ss[2] + ss[3];
        float SQ = ssq[0] + ssq[1] + ssq[2] + ssq[3];
        float m  = S * (1.0f / DMODEL);
        float var = SQ * (1.0f / DMODEL) - m * m;
        mean_s = m;
        rstd_s = rsqrtf(var + 1e-5f);
    }
    __syncthreads();
    float m = mean_s, rs = rstd_s;
    float* orow = out + (size_t)row * DMODEL;
#pragma unroll
    for (int j = 0; j < 3; j++) {
        int i = tid + j * 256;
        orow[i] = (v[j] - m) * rs * w[i] + b[i];
    }
}

// ---------------------------------------------------------------------------
// Generic fp32 GEMM: C[M,N] = A[M,K] @ W[K,N] (+ bias) (+ softplus if act==1)
// 64x64 tile per 256-thread block, 4x4 per thread, BK=16.
// ---------------------------------------------------------------------------
#define BM 64
#define BN 64
#define BK 16
__global__ __launch_bounds__(256) void gemm_kernel(
    const float* __restrict__ A, int lda,
    const float* __restrict__ W, int ldw,
    const float* __restrict__ bias,
    float* __restrict__ C, int ldc,
    int M, int N, int K, int act)
{
    __shared__ float As[BK][BM + 4];
    __shared__ float Bs[BK][BN + 4];
    int tid = threadIdx.x;
    int m0 = blockIdx.y * BM;
    int n0 = blockIdx.x * BN;
    int tx = tid & 15, ty = tid >> 4;
    float acc[4][4] = {};

    for (int k0 = 0; k0 < K; k0 += BK) {
        // --- A tile: 64 rows x 16 k (M=4096 -> rows always in-bounds)
        {
            int row = tid >> 2;
            int kq  = (tid & 3) * 4;
            const float* ap = A + (size_t)(m0 + row) * lda + k0 + kq;
            float4 av;
            if (k0 + BK <= K) {
                av = *(const float4*)ap;
            } else {
                float t0 = (k0 + kq + 0 < K) ? ap[0] : 0.f;
                float t1 = (k0 + kq + 1 < K) ? ap[1] : 0.f;
                float t2 = (k0 + kq + 2 < K) ? ap[2] : 0.f;
                float t3 = (k0 + kq + 3 < K) ? ap[3] : 0.f;
                av = make_float4(t0, t1, t2, t3);
            }
            As[kq + 0][row] = av.x;
            As[kq + 1][row] = av.y;
            As[kq + 2][row] = av.z;
            As[kq + 3][row] = av.w;
        }
        // --- B tile: 16 k x 64 n
        {
            int krow = tid >> 4;
            int col  = (tid & 15) * 4;
            float4 wv = make_float4(0.f, 0.f, 0.f, 0.f);
            if (k0 + krow < K) {
                const float* wp = W + (size_t)(k0 + krow) * ldw + n0 + col;
                if (n0 + col + 3 < N) {
                    wv = *(const float4*)wp;
                } else {
                    float t0 = (n0 + col + 0 < N) ? wp[0] : 0.f;
                    float t1 = (n0 + col + 1 < N) ? wp[1] : 0.f;
                    float t2 = (n0 + col + 2 < N) ? wp[2] : 0.f;
                    float t3 = (n0 + col + 3 < N) ? wp[3] : 0.f;
                    wv = make_float4(t0, t1, t2, t3);
                }
            }
            *(float4*)&Bs[krow][col] = wv;
        }
        __syncthreads();
#pragma unroll
        for (int k = 0; k < BK; k++) {
            float a[4], bv[4];
            *(float4*)a  = *(const float4*)&As[k][ty * 4];
            *(float4*)bv = *(const float4*)&Bs[k][tx * 4];
#pragma unroll
            for (int i = 0; i < 4; i++)
#pragma unroll
                for (int j = 0; j < 4; j++)
                    acc[i][j] = fmaf(a[i], bv[j], acc[i][j]);
        }
        __syncthreads();
    }
#pragma unroll
    for (int i = 0; i < 4; i++) {
        int m = m0 + ty * 4 + i;
#pragma unroll
        for (int j = 0; j < 4; j++) {
            int n = n0 + tx * 4 + j;
            if (n < N) {
                float v = acc[i][j] + (bias ? bias[n] : 0.f);
                if (act == 1) v = (v > 20.f) ? v : log1pf(__expf(v));
                C[(size_t)m * ldc + n] = v;
            }
        }
    }
}

// ---------------------------------------------------------------------------
// Causal conv1d (K=4) + SiLU. rev==1 runs anticausal (backward direction).
// ---------------------------------------------------------------------------
__global__ __launch_bounds__(256) void conv_silu_kernel(
    const float* __restrict__ xz,
    const float* __restrict__ cw, const float* __restrict__ cb,
    float* __restrict__ out, int rev)
{
    int idx = blockIdx.x * 256 + threadIdx.x;
    if (idx >= ROWS * DINNER) return;
    int d = idx % DINNER;
    int row = idx / DINNER;
    int t = row & (SEQ - 1);
    int b = row >> 11;
    float acc = cb[d];
#pragma unroll
    for (int k = 0; k < 4; k++) {
        int ts = rev ? (t + 3 - k) : (t - 3 + k);
        if (ts >= 0 && ts < SEQ)
            acc = fmaf(cw[d * 4 + k], xz[((size_t)(b * SEQ + ts)) * 1536 + d], acc);
    }
    float sig = 1.f / (1.f + __expf(-acc));
    out[idx] = acc * sig;
}

// ---------------------------------------------------------------------------
// Chunked selective scan, thread = one channel, h[16] in registers.
// FULL=false: pass 1 -- local scan from h=0, emit Hloc[16], W[16]=exp(a*sum_dt).
// FULL=true : pass 2 -- scan seeded with Hin, emit y=(h.C + x*D)*silu(z).
// Fast path: a_n ~= n*a_1 (A_log = log(arange)) -> 1 exp + mul tree instead of
// 16 exps per step; verified per-thread against loaded A_log, exact fallback.
// ---------------------------------------------------------------------------
template<bool FULL>
__global__ __launch_bounds__(256) void scan_chunk_kernel(
    const float* __restrict__ dtf, const float* __restrict__ xcf,
    const float* __restrict__ xdf, const float* __restrict__ xzf,
    const float* __restrict__ Alf, const float* __restrict__ Dff,
    const float* __restrict__ dtb, const float* __restrict__ xcb,
    const float* __restrict__ xdb, const float* __restrict__ xzb,
    const float* __restrict__ Alb, const float* __restrict__ Dbb,
    float* __restrict__ Hloc, float* __restrict__ Wp,
    const float* __restrict__ Hin,
    float* __restrict__ yf, float* __restrict__ yb)
{
    const int d     = blockIdx.x * 256 + threadIdx.x;   // channel 0..767
    const int chunk = blockIdx.y;                       // 0..NCH-1
    const int bz    = blockIdx.z;                       // dirbat 0..3
    const int dir   = bz >> 1;
    const int bat   = bz & 1;

    const float* dt = dir ? dtb : dtf;
    const float* xc = dir ? xcb : xcf;
    const float* xd = dir ? xdb : xdf;
    const float* xz = dir ? xzb : xzf;
    const float* Al = dir ? Alb : Alf;
    const float* Dp = dir ? Dbb : Dff;
    float* yo = dir ? yb : yf;

    // a_n = -exp(A_log[d][n])
    float a[16];
    {
        const float4* Ap = (const float4*)(Al + (size_t)d * 16);
#pragma unroll
        for (int q = 0; q < 4; q++) {
            float4 v = Ap[q];
            a[q*4+0] = -__expf(v.x); a[q*4+1] = -__expf(v.y);
            a[q*4+2] = -__expf(v.z); a[q*4+3] = -__expf(v.w);
        }
    }
    const float a0 = a[0];
    bool fast = true;
#pragma unroll
    for (int n = 0; n < 16; n++) {
        float ideal = a0 * (float)(n + 1);
        fast = fast && (fabsf(a[n] - ideal) <= 1e-4f * fabsf(ideal) + 1e-7f);
    }

    float h[16];
    if (FULL) {
        size_t base = ((size_t)(bz * NCH + chunk) * DINNER + d) * 16;
        const float4* hp = (const float4*)(Hin + base);
#pragma unroll
        for (int q = 0; q < 4; q++) {
            float4 v = hp[q];
            h[q*4+0] = v.x; h[q*4+1] = v.y; h[q*4+2] = v.z; h[q*4+3] = v.w;
        }
    } else {
#pragma unroll
        for (int n = 0; n < 16; n++) h[n] = 0.f;
    }

    const float Dd = FULL ? Dp[d] : 0.f;
    float S = 0.f;

    auto run = [&](auto FASTC) {
        constexpr bool FAST = decltype(FASTC)::value;
#pragma unroll 2
        for (int i = 0; i < CLEN; i++) {
            int tl = chunk * CLEN + i;               // logical scan time
            int t  = dir ? (SEQ - 1 - tl) : tl;      // physical time
            size_t r = (size_t)(bat * SEQ + t);
            float dtv = dt[r * DINNER + d];
            float xv  = xc[r * DINNER + d];
            const float* bp = xd + r * 56 + DTRANK;  // wave-uniform address
            float4 B0 = *(const float4*)(bp + 0);
            float4 B1 = *(const float4*)(bp + 4);
            float4 B2 = *(const float4*)(bp + 8);
            float4 B3 = *(const float4*)(bp + 12);
            float Bv[16] = {B0.x,B0.y,B0.z,B0.w, B1.x,B1.y,B1.z,B1.w,
                            B2.x,B2.y,B2.z,B2.w, B3.x,B3.y,B3.z,B3.w};
            float w[16];
            if (FAST) {
                float e1 = __expf(dtv * a0);
                float e2 = e1*e1, e4 = e2*e2, e8 = e4*e4;
                w[0]=e1;      w[1]=e2;      w[2]=e2*e1;   w[3]=e4;
                w[4]=e4*e1;   w[5]=e4*e2;   w[6]=e4*w[2]; w[7]=e8;
                w[8]=e8*e1;   w[9]=e8*e2;   w[10]=e8*w[2];w[11]=e8*e4;
                w[12]=e8*w[4];w[13]=e8*w[5];w[14]=e8*w[6];w[15]=e8*e8;
            } else {
#pragma unroll
                for (int n = 0; n < 16; n++) w[n] = __expf(dtv * a[n]);
            }
            float bx = dtv * xv;
#pragma unroll
            for (int n = 0; n < 16; n++)
                h[n] = fmaf(w[n], h[n], bx * Bv[n]);
            S += dtv;
            if (FULL) {
                const float* cp = bp + DSTATE;
                float4 C0 = *(const float4*)(cp + 0);
                float4 C1 = *(const float4*)(cp + 4);
                float4 C2 = *(const float4*)(cp + 8);
                float4 C3 = *(const float4*)(cp + 12);
                float Cv[16] = {C0.x,C0.y,C0.z,C0.w, C1.x,C1.y,C1.z,C1.w,
                                C2.x,C2.y,C2.z,C2.w, C3.x,C3.y,C3.z,C3.w};
                float y = 0.f;
#pragma unroll
                for (int n = 0; n < 16; n++) y = fmaf(h[n], Cv[n], y);
                float zv = xz[r * 1536 + DINNER + d];
                float sig = 1.f / (1.f + __expf(-zv));
                yo[r * DINNER + d] = (y + xv * Dd) * (zv * sig);
            }
        }
    };
    if (fast) run(std::true_type{}); else run(std::false_type{});

    if (!FULL) {
        float W[16];
        if (fast) {
            float E1 = __expf(S * a0);
            float E2 = E1*E1, E4 = E2*E2, E8 = E4*E4;
            W[0]=E1;      W[1]=E2;      W[2]=E2*E1;   W[3]=E4;
            W[4]=E4*E1;   W[5]=E4*E2;   W[6]=E4*W[2]; W[7]=E8;
            W[8]=E8*E1;   W[9]=E8*E2;   W[10]=E8*W[2];W[11]=E8*E4;
            W[12]=E8*W[4];W[13]=E8*W[5];W[14]=E8*W[6];W[15]=E8*E8;
        } else {
#pragma unroll
            for (int n = 0; n < 16; n++) W[n] = __expf(S * a[n]);
        }
        size_t base = ((size_t)(bz * NCH + chunk) * DINNER + d) * 16;
#pragma unroll
        for (int q = 0; q < 4; q++) {
            *(float4*)(Hloc + base + q*4) = make_float4(h[q*4+0], h[q*4+1], h[q*4+2], h[q*4+3]);
            *(float4*)(Wp   + base + q*4) = make_float4(W[q*4+0], W[q*4+1], W[q*4+2], W[q*4+3]);
        }
    }
}

// Sequential recombination across chunks: hin_{k+1} = W_k * hin_k + Hloc_k.
// One thread per (dirbat, d, n) = 49152 threads.
__global__ __launch_bounds__(256) void scan_combine(
    const float* __restrict__ Hloc, const float* __restrict__ Wp,
    float* __restrict__ Hin)
{
    int idx = blockIdx.x * 256 + threadIdx.x;
    int bz = idx / (DINNER * 16);
    int rest = idx % (DINNER * 16);
    float hin = 0.f;
#pragma unroll
    for (int k = 0; k < NCH; k++) {
        size_t o = (size_t)(bz * NCH + k) * (DINNER * 16) + rest;
        Hin[o] = hin;
        hin = fmaf(Wp[o], hin, Hloc[o]);
    }
}

// ---------------------------------------------------------------------------
extern "C" void kernel_launch(void* const* d_in, const int* in_sizes, int n_in,
                              void* d_out, int out_size, void* d_ws, size_t ws_size,
                              hipStream_t stream)
{
    const float* x        = (const float*)d_in[0];
    const float* in_nw    = (const float*)d_in[1];
    const float* in_nb    = (const float*)d_in[2];
    const float* ip_w     = (const float*)d_in[3];
    const float* ip_b     = (const float*)d_in[4];
    const float* f_in_w   = (const float*)d_in[5];
    const float* f_in_b   = (const float*)d_in[6];
    const float* f_conv_w = (const float*)d_in[7];
    const float* f_conv_b = (const float*)d_in[8];
    const float* f_xp_w   = (const float*)d_in[9];
    const float* f_dt_w   = (const float*)d_in[10];
    const float* f_dt_b   = (const float*)d_in[11];
    const float* f_A_log  = (const float*)d_in[12];
    const float* f_D      = (const float*)d_in[13];
    const float* f_out_w  = (const float*)d_in[14];
    const float* f_out_b  = (const float*)d_in[15];
    const float* b_in_w   = (const float*)d_in[16];
    const float* b_in_b   = (const float*)d_in[17];
    const float* b_conv_w = (const float*)d_in[18];
    const float* b_conv_b = (const float*)d_in[19];
    const float* b_xp_w   = (const float*)d_in[20];
    const float* b_dt_w   = (const float*)d_in[21];
    const float* b_dt_b   = (const float*)d_in[22];
    const float* b_A_log  = (const float*)d_in[23];
    const float* b_D      = (const float*)d_in[24];
    const float* b_out_w  = (const float*)d_in[25];
    const float* b_out_b  = (const float*)d_in[26];
    const float* op_w     = (const float*)d_in[27];
    const float* op_b     = (const float*)d_in[28];
    const float* norm_w   = (const float*)d_in[29];
    const float* norm_b   = (const float*)d_in[30];

    float* ws = (float*)d_ws;
    const size_t R = ROWS;
    float* xn   = ws;                       // R*768
    float* xp   = xn   + R * 768;           // R*768
    float* xz_f = xp   + R * 768;           // R*1536
    float* xz_b = xz_f + R * 1536;          // R*1536
    float* xc_f = xz_b + R * 1536;          // R*768
    float* xc_b = xc_f + R * 768;           // R*768
    float* xd_f = xc_b + R * 768;           // R*56
    float* xd_b = xd_f + R * 56;            // R*56
    float* dt_f = xd_b + R * 56;            // R*768
    float* dt_b = dt_f + R * 768;           // R*768
    float* y_f  = dt_b + R * 768;           // R*768
    float* y_b  = y_f  + R * 768;           // R*768
    float* cat    = xp;   // reuse: xp dead after xz GEMMs (scan scratch also dead)
    float* outraw = xn;   // reuse: xn dead after xp GEMM (scan scratch also dead)

    // Scan scratch lives in the dead xn+xp region (6.29M floats available,
    // need 3 * 4*NCH*DINNER*16 = 4.72M). All scratch reads finish before
    // out-GEMMs overwrite cat/outraw (stream-ordered).
    const size_t SCN = (size_t)4 * NCH * DINNER * 16;  // 1.57M floats
    float* Hloc = ws;
    float* Wp   = Hloc + SCN;
    float* Hin  = Wp + SCN;

    dim3 blk(256);

    // 1. input layernorm
    hipLaunchKernelGGL(ln_kernel, dim3(ROWS), blk, 0, stream, x, nullptr, in_nw, in_nb, xn);
    // 2. xp = xn @ ip_w + ip_b
    hipLaunchKernelGGL(gemm_kernel, dim3(768 / BN, ROWS / BM), blk, 0, stream,
                       xn, 768, ip_w, 768, ip_b, xp, 768, ROWS, 768, 768, 0);
    // 3/4. xz = split(xp) @ {f,b}_in_w + bias
    hipLaunchKernelGGL(gemm_kernel, dim3(1536 / BN, ROWS / BM), blk, 0, stream,
                       xp, 768, f_in_w, 1536, f_in_b, xz_f, 1536, ROWS, 1536, DIN, 0);
    hipLaunchKernelGGL(gemm_kernel, dim3(1536 / BN, ROWS / BM), blk, 0, stream,
                       xp + DIN, 768, b_in_w, 1536, b_in_b, xz_b, 1536, ROWS, 1536, DIN, 0);
    // 5. conv + silu (direction-aware)
    hipLaunchKernelGGL(conv_silu_kernel, dim3(ROWS * DINNER / 256), blk, 0, stream,
                       xz_f, f_conv_w, f_conv_b, xc_f, 0);
    hipLaunchKernelGGL(conv_silu_kernel, dim3(ROWS * DINNER / 256), blk, 0, stream,
                       xz_b, b_conv_w, b_conv_b, xc_b, 1);
    // 6/7. xd = xc @ xp_w  (N=56)
    hipLaunchKernelGGL(gemm_kernel, dim3(1, ROWS / BM), blk, 0, stream,
                       xc_f, 768, f_xp_w, 56, nullptr, xd_f, 56, ROWS, 56, 768, 0);
    hipLaunchKernelGGL(gemm_kernel, dim3(1, ROWS / BM), blk, 0, stream,
                       xc_b, 768, b_xp_w, 56, nullptr, xd_b, 56, ROWS, 56, 768, 0);
    // 8/9. dt = softplus(xd[:, :24] @ dt_w + dt_b)
    hipLaunchKernelGGL(gemm_kernel, dim3(768 / BN, ROWS / BM), blk, 0, stream,
                       xd_f, 56, f_dt_w, 768, f_dt_b, dt_f, 768, ROWS, 768, DTRANK, 1);
    hipLaunchKernelGGL(gemm_kernel, dim3(768 / BN, ROWS / BM), blk, 0, stream,
                       xd_b, 56, b_dt_w, 768, b_dt_b, dt_b, 768, ROWS, 768, DTRANK, 1);
    // 10. chunked selective scan: pass1 -> combine -> pass2 (fused epilogue)
    hipLaunchKernelGGL((scan_chunk_kernel<false>), dim3(DINNER / 256, NCH, 4), blk, 0, stream,
                       dt_f, xc_f, xd_f, xz_f, f_A_log, f_D,
                       dt_b, xc_b, xd_b, xz_b, b_A_log, b_D,
                       Hloc, Wp, nullptr, nullptr, nullptr);
    hipLaunchKernelGGL(scan_combine, dim3(4 * DINNER * 16 / 256), blk, 0, stream,
                       Hloc, Wp, Hin);
    hipLaunchKernelGGL((scan_chunk_kernel<true>), dim3(DINNER / 256, NCH, 4), blk, 0, stream,
                       dt_f, xc_f, xd_f, xz_f, f_A_log, f_D,
                       dt_b, xc_b, xd_b, xz_b, b_A_log, b_D,
                       nullptr, nullptr, Hin, y_f, y_b);
    // 11/12. out_{f,b} = y @ out_w + out_b -> concat buffer columns
    hipLaunchKernelGGL(gemm_kernel, dim3(DIN / BN, ROWS / BM), blk, 0, stream,
                       y_f, 768, f_out_w, 384, f_out_b, cat, 768, ROWS, 384, 768, 0);
    hipLaunchKernelGGL(gemm_kernel, dim3(DIN / BN, ROWS / BM), blk, 0, stream,
                       y_b, 768, b_out_w, 384, b_out_b, cat + DIN, 768, ROWS, 384, 768, 0);
    // 13. op projection
    hipLaunchKernelGGL(gemm_kernel, dim3(768 / BN, ROWS / BM), blk, 0, stream,
                       cat, 768, op_w, 768, op_b, outraw, 768, ROWS, 768, 768, 0);
    // 14. final layernorm(residual + out)
    hipLaunchKernelGGL(ln_kernel, dim3(ROWS), blk, 0, stream,
                       x, outraw, norm_w, norm_b, (float*)d_out);
}

// Round 3
// 422.336 us; speedup vs baseline: 3.1841x; 1.9334x over previous
//
#include <hip/hip_runtime.h>
#include <hip/hip_bf16.h>
#include <math.h>
#include <type_traits>

#define BATCH 2
#define SEQ   2048
#define DMODEL 768
#define DIN   384
#define DINNER 768
#define DSTATE 16
#define DTRANK 24
#define ROWS  (BATCH*SEQ)   // 4096
#define NCH   32            // time chunks for the scan
#define CLEN  (SEQ/NCH)     // 64 steps per chunk

using short8  = __attribute__((ext_vector_type(8))) short;
using floatx4 = __attribute__((ext_vector_type(4))) float;

__device__ __forceinline__ ushort f2bf(float f) {
    union { float f; uint u; } v; v.f = f;
    uint r = (v.u + 0x7fffu + ((v.u >> 16) & 1u)) >> 16;
    return (ushort)r;
}
__device__ __forceinline__ float bf2f(ushort h) {
    union { uint u; float f; } v; v.u = ((uint)h) << 16;
    return v.f;
}

// ---------------------------------------------------------------------------
// LayerNorm (optionally with residual add). One block per row of 768.
// OUT = ushort (bf16) or float.
// ---------------------------------------------------------------------------
template<typename OUT>
__global__ __launch_bounds__(256) void ln_kernel(
    const float* __restrict__ x, const float* __restrict__ res,
    const float* __restrict__ w, const float* __restrict__ b,
    OUT* __restrict__ out)
{
    int row = blockIdx.x;
    int tid = threadIdx.x;
    const float* xr = x + (size_t)row * DMODEL;
    const float* rr = res ? res + (size_t)row * DMODEL : nullptr;
    float v[3];
    float s = 0.f, sq = 0.f;
#pragma unroll
    for (int j = 0; j < 3; j++) {
        int i = tid + j * 256;
        float val = xr[i];
        if (rr) val += rr[i];
        v[j] = val; s += val; sq += val * val;
    }
#pragma unroll
    for (int off = 32; off; off >>= 1) {
        s  += __shfl_down(s,  off);
        sq += __shfl_down(sq, off);
    }
    __shared__ float ss[4], ssq[4];
    __shared__ float mean_s, rstd_s;
    int wid = tid >> 6;
    if ((tid & 63) == 0) { ss[wid] = s; ssq[wid] = sq; }
    __syncthreads();
    if (tid == 0) {
        float S  = ss[0] + ss[1] + ss[2] + ss[3];
        float SQ = ssq[0] + ssq[1] + ssq[2] + ssq[3];
        float m  = S * (1.0f / DMODEL);
        float var = SQ * (1.0f / DMODEL) - m * m;
        mean_s = m;
        rstd_s = rsqrtf(var + 1e-5f);
    }
    __syncthreads();
    float m = mean_s, rs = rstd_s;
    OUT* orow = out + (size_t)row * DMODEL;
#pragma unroll
    for (int j = 0; j < 3; j++) {
        int i = tid + j * 256;
        float r = (v[j] - m) * rs * w[i] + b[i];
        if constexpr (std::is_same_v<OUT, ushort>) orow[i] = f2bf(r);
        else                                       orow[i] = r;
    }
}

// ---------------------------------------------------------------------------
// Transpose+cast all weights fp32 W[K][N] -> bf16 Wt[Np][K] (zero pad N..Np).
// One launch for all 8 weights via a descriptor table.
// ---------------------------------------------------------------------------
struct TD { const float* src; ushort* dst; int K, N, Np, tile0, tk; };
struct TDs { TD d[8]; };

__global__ __launch_bounds__(256) void tcast_kernel(TDs ds)
{
    int bidx = blockIdx.x;
    int i = 0;
    while (i < 7 && bidx >= ds.d[i + 1].tile0) i++;
    TD t = ds.d[i];
    int local = bidx - t.tile0;
    int tk = local % t.tk, tn = local / t.tk;
    int tx = threadIdx.x & 31, ty = threadIdx.x >> 5;

    __shared__ float tile[32][33];
    int k0 = tk * 32, n0 = tn * 32;
#pragma unroll
    for (int r = ty; r < 32; r += 8) {
        int n = n0 + tx;
        tile[r][tx] = (n < t.N) ? t.src[(size_t)(k0 + r) * t.N + n] : 0.f;
    }
    __syncthreads();
#pragma unroll
    for (int r = ty; r < 32; r += 8) {
        int n = n0 + r, k = k0 + tx;
        t.dst[(size_t)n * t.K + k] = f2bf(tile[tx][r]);
    }
}

// ---------------------------------------------------------------------------
// bf16 MFMA GEMM: C[M,N] = A[M,K] @ Bt[N,K]^T (+bias). 16x16x32 bf16 MFMA.
// TM x TN block tile, 256 threads = 4 waves (2x2), BK=32.
// ---------------------------------------------------------------------------
template<int TM, int TN, bool OUT_BF>
__global__ __launch_bounds__(256) void mfma_gemm(
    const ushort* __restrict__ A, int lda,
    const ushort* __restrict__ Bt, int ldb,
    const float* __restrict__ bias,
    void* __restrict__ Cout, int ldc, int N, int K)
{
    constexpr int WM = TM / 2, WN = TN / 2;
    constexpr int MT = WM / 16, NT = WN / 16;
    constexpr int LST = 48;                  // LDS row stride (shorts), 96B
    __shared__ ushort lA[TM * LST];
    __shared__ ushort lB[TN * LST];
    const int tid = threadIdx.x;
    const int wave = tid >> 6, lane = tid & 63;
    const int wm = wave >> 1, wn = wave & 1;
    const int quad = lane >> 4, l16 = lane & 15;
    const int m0 = blockIdx.y * TM, n0 = blockIdx.x * TN;

    floatx4 acc[MT][NT];
#pragma unroll
    for (int i = 0; i < MT; i++)
#pragma unroll
        for (int j = 0; j < NT; j++)
            acc[i][j] = (floatx4){0.f, 0.f, 0.f, 0.f};

    constexpr int CHA = TM * 4 / 256;   // 8-short chunks per thread for A tile
    constexpr int CHB = TN * 4 / 256;

    for (int k0 = 0; k0 < K; k0 += 32) {
#pragma unroll
        for (int c = 0; c < CHA; c++) {
            int f = tid + c * 256;
            int row = f >> 2, kc = (f & 3) * 8;
            uint4 v = *(const uint4*)(A + (size_t)(m0 + row) * lda + k0 + kc);
            *(uint4*)&lA[row * LST + kc] = v;
        }
#pragma unroll
        for (int c = 0; c < CHB; c++) {
            int f = tid + c * 256;
            int row = f >> 2, kc = (f & 3) * 8;
            uint4 v = *(const uint4*)(Bt + (size_t)(n0 + row) * ldb + k0 + kc);
            *(uint4*)&lB[row * LST + kc] = v;
        }
        __syncthreads();
        short8 af[MT], bfr[NT];
#pragma unroll
        for (int i = 0; i < MT; i++)
            af[i] = *(const short8*)&lA[(wm * WM + i * 16 + l16) * LST + quad * 8];
#pragma unroll
        for (int j = 0; j < NT; j++)
            bfr[j] = *(const short8*)&lB[(wn * WN + j * 16 + l16) * LST + quad * 8];
#pragma unroll
        for (int i = 0; i < MT; i++)
#pragma unroll
            for (int j = 0; j < NT; j++)
                acc[i][j] = __builtin_amdgcn_mfma_f32_16x16x32_bf16(af[i], bfr[j], acc[i][j], 0, 0, 0);
        __syncthreads();
    }
#pragma unroll
    for (int i = 0; i < MT; i++) {
#pragma unroll
        for (int j = 0; j < NT; j++) {
            int row = m0 + wm * WM + i * 16 + quad * 4;
            int col = n0 + wn * WN + j * 16 + l16;
            if (col < N) {
                float bv = bias ? bias[col] : 0.f;
#pragma unroll
                for (int r = 0; r < 4; r++) {
                    float v = acc[i][j][r] + bv;
                    if (OUT_BF) ((ushort*)Cout)[(size_t)(row + r) * ldc + col] = f2bf(v);
                    else        ((float*)Cout)[(size_t)(row + r) * ldc + col] = v;
                }
            }
        }
    }
}

// ---------------------------------------------------------------------------
// fp32 GEMM (kept for the tiny K=24 dt projection, with softplus).
// ---------------------------------------------------------------------------
#define BM 64
#define BN 64
#define BK 16
__global__ __launch_bounds__(256) void gemm_kernel(
    const float* __restrict__ A, int lda,
    const float* __restrict__ W, int ldw,
    const float* __restrict__ bias,
    float* __restrict__ C, int ldc,
    int M, int N, int K, int act)
{
    __shared__ float As[BK][BM + 4];
    __shared__ float Bs[BK][BN + 4];
    int tid = threadIdx.x;
    int m0 = blockIdx.y * BM;
    int n0 = blockIdx.x * BN;
    int tx = tid & 15, ty = tid >> 4;
    float acc[4][4] = {};

    for (int k0 = 0; k0 < K; k0 += BK) {
        {
            int row = tid >> 2;
            int kq  = (tid & 3) * 4;
            const float* ap = A + (size_t)(m0 + row) * lda + k0 + kq;
            float4 av;
            if (k0 + BK <= K) {
                av = *(const float4*)ap;
            } else {
                float t0 = (k0 + kq + 0 < K) ? ap[0] : 0.f;
                float t1 = (k0 + kq + 1 < K) ? ap[1] : 0.f;
                float t2 = (k0 + kq + 2 < K) ? ap[2] : 0.f;
                float t3 = (k0 + kq + 3 < K) ? ap[3] : 0.f;
                av = make_float4(t0, t1, t2, t3);
            }
            As[kq + 0][row] = av.x;
            As[kq + 1][row] = av.y;
            As[kq + 2][row] = av.z;
            As[kq + 3][row] = av.w;
        }
        {
            int krow = tid >> 4;
            int col  = (tid & 15) * 4;
            float4 wv = make_float4(0.f, 0.f, 0.f, 0.f);
            if (k0 + krow < K) {
                const float* wp = W + (size_t)(k0 + krow) * ldw + n0 + col;
                if (n0 + col + 3 < N) {
                    wv = *(const float4*)wp;
                } else {
                    float t0 = (n0 + col + 0 < N) ? wp[0] : 0.f;
                    float t1 = (n0 + col + 1 < N) ? wp[1] : 0.f;
                    float t2 = (n0 + col + 2 < N) ? wp[2] : 0.f;
                    float t3 = (n0 + col + 3 < N) ? wp[3] : 0.f;
                    wv = make_float4(t0, t1, t2, t3);
                }
            }
            *(float4*)&Bs[krow][col] = wv;
        }
        __syncthreads();
#pragma unroll
        for (int k = 0; k < BK; k++) {
            float a[4], bv[4];
            *(float4*)a  = *(const float4*)&As[k][ty * 4];
            *(float4*)bv = *(const float4*)&Bs[k][tx * 4];
#pragma unroll
            for (int i = 0; i < 4; i++)
#pragma unroll
                for (int j = 0; j < 4; j++)
                    acc[i][j] = fmaf(a[i], bv[j], acc[i][j]);
        }
        __syncthreads();
    }
#pragma unroll
    for (int i = 0; i < 4; i++) {
        int m = m0 + ty * 4 + i;
#pragma unroll
        for (int j = 0; j < 4; j++) {
            int n = n0 + tx * 4 + j;
            if (n < N) {
                float v = acc[i][j] + (bias ? bias[n] : 0.f);
                if (act == 1) v = (v > 20.f) ? v : log1pf(__expf(v));
                C[(size_t)m * ldc + n] = v;
            }
        }
    }
}

// ---------------------------------------------------------------------------
// Causal conv1d (K=4) + SiLU, bf16 in/out. rev==1 anticausal.
// ---------------------------------------------------------------------------
__global__ __launch_bounds__(256) void conv_silu_kernel(
    const ushort* __restrict__ xz,
    const float* __restrict__ cw, const float* __restrict__ cb,
    ushort* __restrict__ out, int rev)
{
    int idx = blockIdx.x * 256 + threadIdx.x;
    if (idx >= ROWS * DINNER) return;
    int d = idx % DINNER;
    int row = idx / DINNER;
    int t = row & (SEQ - 1);
    int b = row >> 11;
    float acc = cb[d];
#pragma unroll
    for (int k = 0; k < 4; k++) {
        int ts = rev ? (t + 3 - k) : (t - 3 + k);
        if (ts >= 0 && ts < SEQ)
            acc = fmaf(cw[d * 4 + k], bf2f(xz[((size_t)(b * SEQ + ts)) * 1536 + d]), acc);
    }
    float sig = 1.f / (1.f + __expf(-acc));
    out[idx] = f2bf(acc * sig);
}

// ---------------------------------------------------------------------------
// Chunked selective scan (see R2 notes). dt/xd fp32; xc/xz/y bf16.
// ---------------------------------------------------------------------------
template<bool FULL>
__global__ __launch_bounds__(256) void scan_chunk_kernel(
    const float* __restrict__ dtf, const ushort* __restrict__ xcf,
    const float* __restrict__ xdf, const ushort* __restrict__ xzf,
    const float* __restrict__ Alf, const float* __restrict__ Dff,
    const float* __restrict__ dtb, const ushort* __restrict__ xcb,
    const float* __restrict__ xdb, const ushort* __restrict__ xzb,
    const float* __restrict__ Alb, const float* __restrict__ Dbb,
    float* __restrict__ Hloc, float* __restrict__ Wp,
    const float* __restrict__ Hin,
    ushort* __restrict__ yf, ushort* __restrict__ yb)
{
    const int d     = blockIdx.x * 256 + threadIdx.x;
    const int chunk = blockIdx.y;
    const int bz    = blockIdx.z;
    const int dir   = bz >> 1;
    const int bat   = bz & 1;

    const float*  dt = dir ? dtb : dtf;
    const ushort* xc = dir ? xcb : xcf;
    const float*  xd = dir ? xdb : xdf;
    const ushort* xz = dir ? xzb : xzf;
    const float*  Al = dir ? Alb : Alf;
    const float*  Dp = dir ? Dbb : Dff;
    ushort* yo = dir ? yb : yf;

    float a[16];
    {
        const float4* Ap = (const float4*)(Al + (size_t)d * 16);
#pragma unroll
        for (int q = 0; q < 4; q++) {
            float4 v = Ap[q];
            a[q*4+0] = -__expf(v.x); a[q*4+1] = -__expf(v.y);
            a[q*4+2] = -__expf(v.z); a[q*4+3] = -__expf(v.w);
        }
    }
    const float a0 = a[0];
    bool fast = true;
#pragma unroll
    for (int n = 0; n < 16; n++) {
        float ideal = a0 * (float)(n + 1);
        fast = fast && (fabsf(a[n] - ideal) <= 1e-4f * fabsf(ideal) + 1e-7f);
    }

    float h[16];
    if (FULL) {
        size_t base = ((size_t)(bz * NCH + chunk) * DINNER + d) * 16;
        const float4* hp = (const float4*)(Hin + base);
#pragma unroll
        for (int q = 0; q < 4; q++) {
            float4 v = hp[q];
            h[q*4+0] = v.x; h[q*4+1] = v.y; h[q*4+2] = v.z; h[q*4+3] = v.w;
        }
    } else {
#pragma unroll
        for (int n = 0; n < 16; n++) h[n] = 0.f;
    }

    const float Dd = FULL ? Dp[d] : 0.f;
    float S = 0.f;

    auto run = [&](auto FASTC) {
        constexpr bool FAST = decltype(FASTC)::value;
#pragma unroll 2
        for (int i = 0; i < CLEN; i++) {
            int tl = chunk * CLEN + i;
            int t  = dir ? (SEQ - 1 - tl) : tl;
            size_t r = (size_t)(bat * SEQ + t);
            float dtv = dt[r * DINNER + d];
            float xv  = bf2f(xc[r * DINNER + d]);
            const float* bp = xd + r * 56 + DTRANK;
            float4 B0 = *(const float4*)(bp + 0);
            float4 B1 = *(const float4*)(bp + 4);
            float4 B2 = *(const float4*)(bp + 8);
            float4 B3 = *(const float4*)(bp + 12);
            float Bv[16] = {B0.x,B0.y,B0.z,B0.w, B1.x,B1.y,B1.z,B1.w,
                            B2.x,B2.y,B2.z,B2.w, B3.x,B3.y,B3.z,B3.w};
            float w[16];
            if (FAST) {
                float e1 = __expf(dtv * a0);
                float e2 = e1*e1, e4 = e2*e2, e8 = e4*e4;
                w[0]=e1;      w[1]=e2;      w[2]=e2*e1;   w[3]=e4;
                w[4]=e4*e1;   w[5]=e4*e2;   w[6]=e4*w[2]; w[7]=e8;
                w[8]=e8*e1;   w[9]=e8*e2;   w[10]=e8*w[2];w[11]=e8*e4;
                w[12]=e8*w[4];w[13]=e8*w[5];w[14]=e8*w[6];w[15]=e8*e8;
            } else {
#pragma unroll
                for (int n = 0; n < 16; n++) w[n] = __expf(dtv * a[n]);
            }
            float bx = dtv * xv;
#pragma unroll
            for (int n = 0; n < 16; n++)
                h[n] = fmaf(w[n], h[n], bx * Bv[n]);
            S += dtv;
            if (FULL) {
                const float* cp = bp + DSTATE;
                float4 C0 = *(const float4*)(cp + 0);
                float4 C1 = *(const float4*)(cp + 4);
                float4 C2 = *(const float4*)(cp + 8);
                float4 C3 = *(const float4*)(cp + 12);
                float Cv[16] = {C0.x,C0.y,C0.z,C0.w, C1.x,C1.y,C1.z,C1.w,
                                C2.x,C2.y,C2.z,C2.w, C3.x,C3.y,C3.z,C3.w};
                float y = 0.f;
#pragma unroll
                for (int n = 0; n < 16; n++) y = fmaf(h[n], Cv[n], y);
                float zv = bf2f(xz[r * 1536 + DINNER + d]);
                float sig = 1.f / (1.f + __expf(-zv));
                yo[r * DINNER + d] = f2bf((y + xv * Dd) * (zv * sig));
            }
        }
    };
    if (fast) run(std::true_type{}); else run(std::false_type{});

    if (!FULL) {
        float W[16];
        if (fast) {
            float E1 = __expf(S * a0);
            float E2 = E1*E1, E4 = E2*E2, E8 = E4*E4;
            W[0]=E1;      W[1]=E2;      W[2]=E2*E1;   W[3]=E4;
            W[4]=E4*E1;   W[5]=E4*E2;   W[6]=E4*W[2]; W[7]=E8;
            W[8]=E8*E1;   W[9]=E8*E2;   W[10]=E8*W[2];W[11]=E8*E4;
            W[12]=E8*W[4];W[13]=E8*W[5];W[14]=E8*W[6];W[15]=E8*E8;
        } else {
#pragma unroll
            for (int n = 0; n < 16; n++) W[n] = __expf(S * a[n]);
        }
        size_t base = ((size_t)(bz * NCH + chunk) * DINNER + d) * 16;
#pragma unroll
        for (int q = 0; q < 4; q++) {
            *(float4*)(Hloc + base + q*4) = make_float4(h[q*4+0], h[q*4+1], h[q*4+2], h[q*4+3]);
            *(float4*)(Wp   + base + q*4) = make_float4(W[q*4+0], W[q*4+1], W[q*4+2], W[q*4+3]);
        }
    }
}

__global__ __launch_bounds__(256) void scan_combine(
    const float* __restrict__ Hloc, const float* __restrict__ Wp,
    float* __restrict__ Hin)
{
    int idx = blockIdx.x * 256 + threadIdx.x;
    int bz = idx / (DINNER * 16);
    int rest = idx % (DINNER * 16);
    float hin = 0.f;
#pragma unroll
    for (int k = 0; k < NCH; k++) {
        size_t o = (size_t)(bz * NCH + k) * (DINNER * 16) + rest;
        Hin[o] = hin;
        hin = fmaf(Wp[o], hin, Hloc[o]);
    }
}

// ---------------------------------------------------------------------------
extern "C" void kernel_launch(void* const* d_in, const int* in_sizes, int n_in,
                              void* d_out, int out_size, void* d_ws, size_t ws_size,
                              hipStream_t stream)
{
    const float* x        = (const float*)d_in[0];
    const float* in_nw    = (const float*)d_in[1];
    const float* in_nb    = (const float*)d_in[2];
    const float* ip_w     = (const float*)d_in[3];
    const float* ip_b     = (const float*)d_in[4];
    const float* f_in_w   = (const float*)d_in[5];
    const float* f_in_b   = (const float*)d_in[6];
    const float* f_conv_w = (const float*)d_in[7];
    const float* f_conv_b = (const float*)d_in[8];
    const float* f_xp_w   = (const float*)d_in[9];
    const float* f_dt_w   = (const float*)d_in[10];
    const float* f_dt_b   = (const float*)d_in[11];
    const float* f_A_log  = (const float*)d_in[12];
    const float* f_D      = (const float*)d_in[13];
    const float* f_out_w  = (const float*)d_in[14];
    const float* f_out_b  = (const float*)d_in[15];
    const float* b_in_w   = (const float*)d_in[16];
    const float* b_in_b   = (const float*)d_in[17];
    const float* b_conv_w = (const float*)d_in[18];
    const float* b_conv_b = (const float*)d_in[19];
    const float* b_xp_w   = (const float*)d_in[20];
    const float* b_dt_w   = (const float*)d_in[21];
    const float* b_dt_b   = (const float*)d_in[22];
    const float* b_A_log  = (const float*)d_in[23];
    const float* b_D      = (const float*)d_in[24];
    const float* b_out_w  = (const float*)d_in[25];
    const float* b_out_b  = (const float*)d_in[26];
    const float* op_w     = (const float*)d_in[27];
    const float* op_b     = (const float*)d_in[28];
    const float* norm_w   = (const float*)d_in[29];
    const float* norm_b   = (const float*)d_in[30];

    // ---- workspace layout (256B-aligned slabs) ----
    size_t off = 0;
    auto alloc = [&](size_t bytes) {
        void* p = (char*)d_ws + off;
        off += (bytes + 255) & ~(size_t)255;
        return p;
    };
    const size_t R = ROWS;
    ushort* xn_bf   = (ushort*)alloc(R * 768 * 2);
    ushort* xp_bf   = (ushort*)alloc(R * 768 * 2);
    ushort* xz_f_bf = (ushort*)alloc(R * 1536 * 2);
    ushort* xz_b_bf = (ushort*)alloc(R * 1536 * 2);
    ushort* xc_f_bf = (ushort*)alloc(R * 768 * 2);
    ushort* xc_b_bf = (ushort*)alloc(R * 768 * 2);
    float*  xd_f    = (float*)alloc(R * 56 * 4);
    float*  xd_b    = (float*)alloc(R * 56 * 4);
    float*  dt_f    = (float*)alloc(R * 768 * 4);
    float*  dt_b    = (float*)alloc(R * 768 * 4);
    ushort* y_f_bf  = (ushort*)alloc(R * 768 * 2);
    ushort* y_b_bf  = (ushort*)alloc(R * 768 * 2);
    ushort* cat_bf  = (ushort*)alloc(R * 768 * 2);
    float*  outraw  = (float*)alloc(R * 768 * 4);
    const size_t SCN = (size_t)4 * NCH * DINNER * 16;
    float* Hloc = (float*)alloc(SCN * 4);
    float* Wpb  = (float*)alloc(SCN * 4);
    float* Hin  = (float*)alloc(SCN * 4);
    ushort* Wt_ip   = (ushort*)alloc((size_t)768 * 768 * 2);
    ushort* Wt_fin  = (ushort*)alloc((size_t)1536 * 384 * 2);
    ushort* Wt_bin  = (ushort*)alloc((size_t)1536 * 384 * 2);
    ushort* Wt_fxp  = (ushort*)alloc((size_t)64 * 768 * 2);
    ushort* Wt_bxp  = (ushort*)alloc((size_t)64 * 768 * 2);
    ushort* Wt_fout = (ushort*)alloc((size_t)384 * 768 * 2);
    ushort* Wt_bout = (ushort*)alloc((size_t)384 * 768 * 2);
    ushort* Wt_op   = (ushort*)alloc((size_t)768 * 768 * 2);

    dim3 blk(256);

    // 0. transpose+cast all weights to bf16 W^T (one launch)
    TDs td;
    int tile0 = 0, nd = 0;
    auto add = [&](const float* s, ushort* dst, int K, int N, int Np) {
        td.d[nd] = TD{s, dst, K, N, Np, tile0, K / 32};
        tile0 += (K / 32) * (Np / 32);
        nd++;
    };
    add(ip_w,    Wt_ip,   768, 768, 768);
    add(f_in_w,  Wt_fin,  384, 1536, 1536);
    add(b_in_w,  Wt_bin,  384, 1536, 1536);
    add(f_xp_w,  Wt_fxp,  768, 56, 64);
    add(b_xp_w,  Wt_bxp,  768, 56, 64);
    add(f_out_w, Wt_fout, 768, 384, 384);
    add(b_out_w, Wt_bout, 768, 384, 384);
    add(op_w,    Wt_op,   768, 768, 768);
    hipLaunchKernelGGL(tcast_kernel, dim3(tile0), blk, 0, stream, td);

    // 1. input layernorm -> bf16
    hipLaunchKernelGGL((ln_kernel<ushort>), dim3(ROWS), blk, 0, stream,
                       x, (const float*)nullptr, in_nw, in_nb, xn_bf);
    // 2. xp = xn @ ip_w + ip_b  (bf16 out)
    hipLaunchKernelGGL((mfma_gemm<128,128,true>), dim3(768/128, ROWS/128), blk, 0, stream,
                       xn_bf, 768, Wt_ip, 768, ip_b, (void*)xp_bf, 768, 768, 768);
    // 3/4. xz = split(xp) @ {f,b}_in_w + bias (bf16 out)
    hipLaunchKernelGGL((mfma_gemm<128,128,true>), dim3(1536/128, ROWS/128), blk, 0, stream,
                       xp_bf, 768, Wt_fin, 384, f_in_b, (void*)xz_f_bf, 1536, 1536, 384);
    hipLaunchKernelGGL((mfma_gemm<128,128,true>), dim3(1536/128, ROWS/128), blk, 0, stream,
                       xp_bf + 384, 768, Wt_bin, 384, b_in_b, (void*)xz_b_bf, 1536, 1536, 384);
    // 5. conv + silu
    hipLaunchKernelGGL(conv_silu_kernel, dim3(ROWS * DINNER / 256), blk, 0, stream,
                       xz_f_bf, f_conv_w, f_conv_b, xc_f_bf, 0);
    hipLaunchKernelGGL(conv_silu_kernel, dim3(ROWS * DINNER / 256), blk, 0, stream,
                       xz_b_bf, b_conv_w, b_conv_b, xc_b_bf, 1);
    // 6/7. xd = xc @ xp_w  (fp32 out, N=56 padded to 64)
    hipLaunchKernelGGL((mfma_gemm<64,64,false>), dim3(1, ROWS/64), blk, 0, stream,
                       xc_f_bf, 768, Wt_fxp, 768, (const float*)nullptr, (void*)xd_f, 56, 56, 768);
    hipLaunchKernelGGL((mfma_gemm<64,64,false>), dim3(1, ROWS/64), blk, 0, stream,
                       xc_b_bf, 768, Wt_bxp, 768, (const float*)nullptr, (void*)xd_b, 56, 56, 768);
    // 8/9. dt = softplus(xd[:, :24] @ dt_w + dt_b) (fp32 vector GEMM, K=24)
    hipLaunchKernelGGL(gemm_kernel, dim3(768 / BN, ROWS / BM), blk, 0, stream,
                       xd_f, 56, f_dt_w, 768, f_dt_b, dt_f, 768, ROWS, 768, DTRANK, 1);
    hipLaunchKernelGGL(gemm_kernel, dim3(768 / BN, ROWS / BM), blk, 0, stream,
                       xd_b, 56, b_dt_w, 768, b_dt_b, dt_b, 768, ROWS, 768, DTRANK, 1);
    // 10. chunked selective scan
    hipLaunchKernelGGL((scan_chunk_kernel<false>), dim3(DINNER / 256, NCH, 4), blk, 0, stream,
                       dt_f, xc_f_bf, xd_f, xz_f_bf, f_A_log, f_D,
                       dt_b, xc_b_bf, xd_b, xz_b_bf, b_A_log, b_D,
                       Hloc, Wpb, (const float*)nullptr, (ushort*)nullptr, (ushort*)nullptr);
    hipLaunchKernelGGL(scan_combine, dim3(4 * DINNER * 16 / 256), blk, 0, stream,
                       Hloc, Wpb, Hin);
    hipLaunchKernelGGL((scan_chunk_kernel<true>), dim3(DINNER / 256, NCH, 4), blk, 0, stream,
                       dt_f, xc_f_bf, xd_f, xz_f_bf, f_A_log, f_D,
                       dt_b, xc_b_bf, xd_b, xz_b_bf, b_A_log, b_D,
                       (float*)nullptr, (float*)nullptr, Hin, y_f_bf, y_b_bf);
    // 11/12. out_{f,b} = y @ out_w + out_b -> concat (bf16)
    hipLaunchKernelGGL((mfma_gemm<128,128,true>), dim3(384/128, ROWS/128), blk, 0, stream,
                       y_f_bf, 768, Wt_fout, 768, f_out_b, (void*)cat_bf, 768, 384, 768);
    hipLaunchKernelGGL((mfma_gemm<128,128,true>), dim3(384/128, ROWS/128), blk, 0, stream,
                       y_b_bf, 768, Wt_bout, 768, b_out_b, (void*)(cat_bf + 384), 768, 384, 768);
    // 13. op projection (fp32 out)
    hipLaunchKernelGGL((mfma_gemm<128,128,false>), dim3(768/128, ROWS/128), blk, 0, stream,
                       cat_bf, 768, Wt_op, 768, op_b, (void*)outraw, 768, 768, 768);
    // 14. final layernorm(residual + out) -> fp32 d_out
    hipLaunchKernelGGL((ln_kernel<float>), dim3(ROWS), blk, 0, stream,
                       x, outraw, norm_w, norm_b, (float*)d_out);
}

// Round 4
// 352.284 us; speedup vs baseline: 3.8173x; 1.1989x over previous
//
#include <hip/hip_runtime.h>
#include <hip/hip_bf16.h>
#include <math.h>
#include <type_traits>

#define BATCH 2
#define SEQ   2048
#define DMODEL 768
#define DIN   384
#define DINNER 768
#define DSTATE 16
#define DTRANK 24
#define ROWS  (BATCH*SEQ)   // 4096
#define NCH   32            // time chunks for the scan
#define CLEN  (SEQ/NCH)     // 64 steps per chunk

using short8  = __attribute__((ext_vector_type(8))) short;
using floatx4 = __attribute__((ext_vector_type(4))) float;

__device__ __forceinline__ ushort f2bf(float f) {
    union { float f; uint u; } v; v.f = f;
    uint r = (v.u + 0x7fffu + ((v.u >> 16) & 1u)) >> 16;
    return (ushort)r;
}
__device__ __forceinline__ float bf2f(ushort h) {
    union { uint u; float f; } v; v.u = ((uint)h) << 16;
    return v.f;
}

// async global->LDS, 16 B per lane; lptr must be wave-uniform (HW adds lane*16)
__device__ __forceinline__ void async16(const ushort* g, ushort* l) {
    __builtin_amdgcn_global_load_lds(
        (const __attribute__((address_space(1))) void*)g,
        (__attribute__((address_space(3))) void*)l,
        16, 0, 0);
}

// ---------------------------------------------------------------------------
// LayerNorm (optionally with residual add). One block per row of 768.
// ---------------------------------------------------------------------------
template<typename OUT>
__global__ __launch_bounds__(256) void ln_kernel(
    const float* __restrict__ x, const float* __restrict__ res,
    const float* __restrict__ w, const float* __restrict__ b,
    OUT* __restrict__ out)
{
    int row = blockIdx.x;
    int tid = threadIdx.x;
    const float* xr = x + (size_t)row * DMODEL;
    const float* rr = res ? res + (size_t)row * DMODEL : nullptr;
    float v[3];
    float s = 0.f, sq = 0.f;
#pragma unroll
    for (int j = 0; j < 3; j++) {
        int i = tid + j * 256;
        float val = xr[i];
        if (rr) val += rr[i];
        v[j] = val; s += val; sq += val * val;
    }
#pragma unroll
    for (int off = 32; off; off >>= 1) {
        s  += __shfl_down(s,  off);
        sq += __shfl_down(sq, off);
    }
    __shared__ float ss[4], ssq[4];
    __shared__ float mean_s, rstd_s;
    int wid = tid >> 6;
    if ((tid & 63) == 0) { ss[wid] = s; ssq[wid] = sq; }
    __syncthreads();
    if (tid == 0) {
        float S  = ss[0] + ss[1] + ss[2] + ss[3];
        float SQ = ssq[0] + ssq[1] + ssq[2] + ssq[3];
        float m  = S * (1.0f / DMODEL);
        float var = SQ * (1.0f / DMODEL) - m * m;
        mean_s = m;
        rstd_s = rsqrtf(var + 1e-5f);
    }
    __syncthreads();
    float m = mean_s, rs = rstd_s;
    OUT* orow = out + (size_t)row * DMODEL;
#pragma unroll
    for (int j = 0; j < 3; j++) {
        int i = tid + j * 256;
        float r = (v[j] - m) * rs * w[i] + b[i];
        if constexpr (std::is_same_v<OUT, ushort>) orow[i] = f2bf(r);
        else                                       orow[i] = r;
    }
}

// ---------------------------------------------------------------------------
// Transpose+cast all weights fp32 W[K][N] -> bf16 Wt[Np][K] (zero pad N..Np).
// ---------------------------------------------------------------------------
struct TD { const float* src; ushort* dst; int K, N, Np, tile0, tk; };
struct TDs { TD d[8]; };

__global__ __launch_bounds__(256) void tcast_kernel(TDs ds)
{
    int bidx = blockIdx.x;
    int i = 0;
    while (i < 7 && bidx >= ds.d[i + 1].tile0) i++;
    TD t = ds.d[i];
    int local = bidx - t.tile0;
    int tk = local % t.tk, tn = local / t.tk;
    int tx = threadIdx.x & 31, ty = threadIdx.x >> 5;

    __shared__ float tile[32][33];
    int k0 = tk * 32, n0 = tn * 32;
#pragma unroll
    for (int r = ty; r < 32; r += 8) {
        int n = n0 + tx;
        tile[r][tx] = (n < t.N) ? t.src[(size_t)(k0 + r) * t.N + n] : 0.f;
    }
    __syncthreads();
#pragma unroll
    for (int r = ty; r < 32; r += 8) {
        int n = n0 + r, k = k0 + tx;
        t.dst[(size_t)n * t.K + k] = f2bf(tile[tx][r]);
    }
}

// ---------------------------------------------------------------------------
// bf16 MFMA GEMM (m97 structure): C[M,N] = A[M,K] @ Bt[N,K]^T (+bias).
// BK=32 (64B LDS rows, no padding), global_load_lds 16B staging,
// ds_read_b128 fragment loads, 16x16x32 MFMA. 256 thr = 4 waves (2x2).
// grid.z selects {A0,B0,bias0,C0} / {A1,...} for fused f/b pairs.
// ---------------------------------------------------------------------------
template<int TM, int TN, bool OUT_BF>
__global__ __launch_bounds__(256) void mfma_gemm(
    const ushort* __restrict__ A0, const ushort* __restrict__ A1, int lda,
    const ushort* __restrict__ B0, const ushort* __restrict__ B1, int ldb,
    const float* __restrict__ bias0, const float* __restrict__ bias1,
    void* __restrict__ C0, void* __restrict__ C1, int ldc, int N, int K)
{
    const ushort* A  = blockIdx.z ? A1 : A0;
    const ushort* Bt = blockIdx.z ? B1 : B0;
    const float* bias = blockIdx.z ? bias1 : bias0;
    void* Cout = blockIdx.z ? C1 : C0;

    constexpr int WM = TM / 2, WN = TN / 2;
    constexpr int MT = WM / 16, NT = WN / 16;
    __shared__ __align__(16) ushort lA[TM * 32];
    __shared__ __align__(16) ushort lB[TN * 32];
    const int tid = threadIdx.x;
    const int wave = tid >> 6, lane = tid & 63;
    const int wm = wave >> 1, wn = wave & 1;
    const int quad = lane >> 4, l16 = lane & 15;
    const int m0 = blockIdx.y * TM, n0 = blockIdx.x * TN;

    // per-lane source row/col for staging instr 0 of this wave
    const int lrow = lane >> 2;            // 16 rows per wave-instr
    const int lcol = (lane & 3) * 8;       // 8 shorts = 16 B

    floatx4 acc[MT][NT];
#pragma unroll
    for (int i = 0; i < MT; i++)
#pragma unroll
        for (int j = 0; j < NT; j++)
            acc[i][j] = (floatx4){0.f, 0.f, 0.f, 0.f};

    constexpr int AI = TM / 64;   // staging wave-instrs per wave for A
    constexpr int BI = TN / 64;

    for (int k0 = 0; k0 < K; k0 += 32) {
#pragma unroll
        for (int i = 0; i < AI; i++) {
            int rbase = (wave * AI + i) * 16;   // first row of this 1KB chunk
            async16(A + (size_t)(m0 + rbase + lrow) * lda + k0 + lcol,
                    &lA[rbase * 32]);
        }
#pragma unroll
        for (int i = 0; i < BI; i++) {
            int rbase = (wave * BI + i) * 16;
            async16(Bt + (size_t)(n0 + rbase + lrow) * ldb + k0 + lcol,
                    &lB[rbase * 32]);
        }
        __syncthreads();
        short8 af[MT], bfr[NT];
#pragma unroll
        for (int i = 0; i < MT; i++)
            af[i] = *(const short8*)&lA[(wm * WM + i * 16 + l16) * 32 + quad * 8];
#pragma unroll
        for (int j = 0; j < NT; j++)
            bfr[j] = *(const short8*)&lB[(wn * WN + j * 16 + l16) * 32 + quad * 8];
#pragma unroll
        for (int i = 0; i < MT; i++)
#pragma unroll
            for (int j = 0; j < NT; j++)
                acc[i][j] = __builtin_amdgcn_mfma_f32_16x16x32_bf16(af[i], bfr[j], acc[i][j], 0, 0, 0);
        __syncthreads();
    }
#pragma unroll
    for (int i = 0; i < MT; i++) {
#pragma unroll
        for (int j = 0; j < NT; j++) {
            int row = m0 + wm * WM + i * 16 + quad * 4;
            int col = n0 + wn * WN + j * 16 + l16;
            if (col < N) {
                float bv = bias ? bias[col] : 0.f;
#pragma unroll
                for (int r = 0; r < 4; r++) {
                    float v = acc[i][j][r] + bv;
                    if (OUT_BF) ((ushort*)Cout)[(size_t)(row + r) * ldc + col] = f2bf(v);
                    else        ((float*)Cout)[(size_t)(row + r) * ldc + col] = v;
                }
            }
        }
    }
}

// ---------------------------------------------------------------------------
// fp32 GEMM for the tiny K=24 dt projection (softplus), f/b fused via grid.z.
// ---------------------------------------------------------------------------
#define BM 64
#define BN 64
#define BK 16
__global__ __launch_bounds__(256) void dt_gemm_kernel(
    const float* __restrict__ A0f, const float* __restrict__ A1f, int lda,
    const float* __restrict__ W0, const float* __restrict__ W1, int ldw,
    const float* __restrict__ bias0, const float* __restrict__ bias1,
    float* __restrict__ C0f, float* __restrict__ C1f, int ldc,
    int M, int N, int K)
{
    const float* A = blockIdx.z ? A1f : A0f;
    const float* W = blockIdx.z ? W1 : W0;
    const float* bias = blockIdx.z ? bias1 : bias0;
    float* C = blockIdx.z ? C1f : C0f;

    __shared__ float As[BK][BM + 4];
    __shared__ float Bs[BK][BN + 4];
    int tid = threadIdx.x;
    int m0 = blockIdx.y * BM;
    int n0 = blockIdx.x * BN;
    int tx = tid & 15, ty = tid >> 4;
    float acc[4][4] = {};

    for (int k0 = 0; k0 < K; k0 += BK) {
        {
            int row = tid >> 2;
            int kq  = (tid & 3) * 4;
            const float* ap = A + (size_t)(m0 + row) * lda + k0 + kq;
            float4 av;
            if (k0 + BK <= K) {
                av = *(const float4*)ap;
            } else {
                float t0 = (k0 + kq + 0 < K) ? ap[0] : 0.f;
                float t1 = (k0 + kq + 1 < K) ? ap[1] : 0.f;
                float t2 = (k0 + kq + 2 < K) ? ap[2] : 0.f;
                float t3 = (k0 + kq + 3 < K) ? ap[3] : 0.f;
                av = make_float4(t0, t1, t2, t3);
            }
            As[kq + 0][row] = av.x;
            As[kq + 1][row] = av.y;
            As[kq + 2][row] = av.z;
            As[kq + 3][row] = av.w;
        }
        {
            int krow = tid >> 4;
            int col  = (tid & 15) * 4;
            float4 wv = make_float4(0.f, 0.f, 0.f, 0.f);
            if (k0 + krow < K) {
                const float* wp = W + (size_t)(k0 + krow) * ldw + n0 + col;
                wv = *(const float4*)wp;
            }
            *(float4*)&Bs[krow][col] = wv;
        }
        __syncthreads();
#pragma unroll
        for (int k = 0; k < BK; k++) {
            float a[4], bv[4];
            *(float4*)a  = *(const float4*)&As[k][ty * 4];
            *(float4*)bv = *(const float4*)&Bs[k][tx * 4];
#pragma unroll
            for (int i = 0; i < 4; i++)
#pragma unroll
                for (int j = 0; j < 4; j++)
                    acc[i][j] = fmaf(a[i], bv[j], acc[i][j]);
        }
        __syncthreads();
    }
#pragma unroll
    for (int i = 0; i < 4; i++) {
        int m = m0 + ty * 4 + i;
#pragma unroll
        for (int j = 0; j < 4; j++) {
            int n = n0 + tx * 4 + j;
            float v = acc[i][j] + bias[n];
            v = (v > 20.f) ? v : log1pf(__expf(v));
            C[(size_t)m * ldc + n] = v;
        }
    }
}

// ---------------------------------------------------------------------------
// Causal conv1d (K=4) + SiLU, bf16 in/out, f/b fused via blockIdx.y (y=dir).
// ---------------------------------------------------------------------------
__global__ __launch_bounds__(256) void conv_silu_kernel(
    const ushort* __restrict__ xzf, const ushort* __restrict__ xzb,
    const float* __restrict__ cwf, const float* __restrict__ cbf,
    const float* __restrict__ cwb, const float* __restrict__ cbb,
    ushort* __restrict__ outf, ushort* __restrict__ outb)
{
    int rev = blockIdx.y;
    const ushort* xz = rev ? xzb : xzf;
    const float* cw = rev ? cwb : cwf;
    const float* cb = rev ? cbb : cbf;
    ushort* out = rev ? outb : outf;

    int idx = blockIdx.x * 256 + threadIdx.x;
    int d = idx % DINNER;
    int row = idx / DINNER;
    int t = row & (SEQ - 1);
    int b = row >> 11;
    float acc = cb[d];
#pragma unroll
    for (int k = 0; k < 4; k++) {
        int ts = rev ? (t + 3 - k) : (t - 3 + k);
        if (ts >= 0 && ts < SEQ)
            acc = fmaf(cw[d * 4 + k], bf2f(xz[((size_t)(b * SEQ + ts)) * 1536 + d]), acc);
    }
    float sig = 1.f / (1.f + __expf(-acc));
    out[idx] = f2bf(acc * sig);
}

// ---------------------------------------------------------------------------
// Chunked selective scan. dt/xd fp32; xc/xz/y bf16. See R2 notes.
// ---------------------------------------------------------------------------
template<bool FULL>
__global__ __launch_bounds__(256) void scan_chunk_kernel(
    const float* __restrict__ dtf, const ushort* __restrict__ xcf,
    const float* __restrict__ xdf, const ushort* __restrict__ xzf,
    const float* __restrict__ Alf, const float* __restrict__ Dff,
    const float* __restrict__ dtb, const ushort* __restrict__ xcb,
    const float* __restrict__ xdb, const ushort* __restrict__ xzb,
    const float* __restrict__ Alb, const float* __restrict__ Dbb,
    float* __restrict__ Hloc, float* __restrict__ Wp,
    const float* __restrict__ Hin,
    ushort* __restrict__ yf, ushort* __restrict__ yb)
{
    const int d     = blockIdx.x * 256 + threadIdx.x;
    const int chunk = blockIdx.y;
    const int bz    = blockIdx.z;
    const int dir   = bz >> 1;
    const int bat   = bz & 1;

    const float*  dt = dir ? dtb : dtf;
    const ushort* xc = dir ? xcb : xcf;
    const float*  xd = dir ? xdb : xdf;
    const ushort* xz = dir ? xzb : xzf;
    const float*  Al = dir ? Alb : Alf;
    const float*  Dp = dir ? Dbb : Dff;
    ushort* yo = dir ? yb : yf;

    float a[16];
    {
        const float4* Ap = (const float4*)(Al + (size_t)d * 16);
#pragma unroll
        for (int q = 0; q < 4; q++) {
            float4 v = Ap[q];
            a[q*4+0] = -__expf(v.x); a[q*4+1] = -__expf(v.y);
            a[q*4+2] = -__expf(v.z); a[q*4+3] = -__expf(v.w);
        }
    }
    const float a0 = a[0];
    bool fast = true;
#pragma unroll
    for (int n = 0; n < 16; n++) {
        float ideal = a0 * (float)(n + 1);
        fast = fast && (fabsf(a[n] - ideal) <= 1e-4f * fabsf(ideal) + 1e-7f);
    }

    float h[16];
    if (FULL) {
        size_t base = ((size_t)(bz * NCH + chunk) * DINNER + d) * 16;
        const float4* hp = (const float4*)(Hin + base);
#pragma unroll
        for (int q = 0; q < 4; q++) {
            float4 v = hp[q];
            h[q*4+0] = v.x; h[q*4+1] = v.y; h[q*4+2] = v.z; h[q*4+3] = v.w;
        }
    } else {
#pragma unroll
        for (int n = 0; n < 16; n++) h[n] = 0.f;
    }

    const float Dd = FULL ? Dp[d] : 0.f;
    float S = 0.f;

    auto run = [&](auto FASTC) {
        constexpr bool FAST = decltype(FASTC)::value;
#pragma unroll 2
        for (int i = 0; i < CLEN; i++) {
            int tl = chunk * CLEN + i;
            int t  = dir ? (SEQ - 1 - tl) : tl;
            size_t r = (size_t)(bat * SEQ + t);
            float dtv = dt[r * DINNER + d];
            float xv  = bf2f(xc[r * DINNER + d]);
            const float* bp = xd + r * 56 + DTRANK;
            float4 B0 = *(const float4*)(bp + 0);
            float4 B1 = *(const float4*)(bp + 4);
            float4 B2 = *(const float4*)(bp + 8);
            float4 B3 = *(const float4*)(bp + 12);
            float Bv[16] = {B0.x,B0.y,B0.z,B0.w, B1.x,B1.y,B1.z,B1.w,
                            B2.x,B2.y,B2.z,B2.w, B3.x,B3.y,B3.z,B3.w};
            float w[16];
            if (FAST) {
                float e1 = __expf(dtv * a0);
                float e2 = e1*e1, e4 = e2*e2, e8 = e4*e4;
                w[0]=e1;      w[1]=e2;      w[2]=e2*e1;   w[3]=e4;
                w[4]=e4*e1;   w[5]=e4*e2;   w[6]=e4*w[2]; w[7]=e8;
                w[8]=e8*e1;   w[9]=e8*e2;   w[10]=e8*w[2];w[11]=e8*e4;
                w[12]=e8*w[4];w[13]=e8*w[5];w[14]=e8*w[6];w[15]=e8*e8;
            } else {
#pragma unroll
                for (int n = 0; n < 16; n++) w[n] = __expf(dtv * a[n]);
            }
            float bx = dtv * xv;
#pragma unroll
            for (int n = 0; n < 16; n++)
                h[n] = fmaf(w[n], h[n], bx * Bv[n]);
            S += dtv;
            if (FULL) {
                const float* cp = bp + DSTATE;
                float4 C0 = *(const float4*)(cp + 0);
                float4 C1 = *(const float4*)(cp + 4);
                float4 C2 = *(const float4*)(cp + 8);
                float4 C3 = *(const float4*)(cp + 12);
                float Cv[16] = {C0.x,C0.y,C0.z,C0.w, C1.x,C1.y,C1.z,C1.w,
                                C2.x,C2.y,C2.z,C2.w, C3.x,C3.y,C3.z,C3.w};
                float y = 0.f;
#pragma unroll
                for (int n = 0; n < 16; n++) y = fmaf(h[n], Cv[n], y);
                float zv = bf2f(xz[r * 1536 + DINNER + d]);
                float sig = 1.f / (1.f + __expf(-zv));
                yo[r * DINNER + d] = f2bf((y + xv * Dd) * (zv * sig));
            }
        }
    };
    if (fast) run(std::true_type{}); else run(std::false_type{});

    if (!FULL) {
        float W[16];
        if (fast) {
            float E1 = __expf(S * a0);
            float E2 = E1*E1, E4 = E2*E2, E8 = E4*E4;
            W[0]=E1;      W[1]=E2;      W[2]=E2*E1;   W[3]=E4;
            W[4]=E4*E1;   W[5]=E4*E2;   W[6]=E4*W[2]; W[7]=E8;
            W[8]=E8*E1;   W[9]=E8*E2;   W[10]=E8*W[2];W[11]=E8*E4;
            W[12]=E8*W[4];W[13]=E8*W[5];W[14]=E8*W[6];W[15]=E8*E8;
        } else {
#pragma unroll
            for (int n = 0; n < 16; n++) W[n] = __expf(S * a[n]);
        }
        size_t base = ((size_t)(bz * NCH + chunk) * DINNER + d) * 16;
#pragma unroll
        for (int q = 0; q < 4; q++) {
            *(float4*)(Hloc + base + q*4) = make_float4(h[q*4+0], h[q*4+1], h[q*4+2], h[q*4+3]);
            *(float4*)(Wp   + base + q*4) = make_float4(W[q*4+0], W[q*4+1], W[q*4+2], W[q*4+3]);
        }
    }
}

__global__ __launch_bounds__(256) void scan_combine(
    const float* __restrict__ Hloc, const float* __restrict__ Wp,
    float* __restrict__ Hin)
{
    int idx = blockIdx.x * 256 + threadIdx.x;
    int bz = idx / (DINNER * 16);
    int rest = idx % (DINNER * 16);
    float hin = 0.f;
#pragma unroll
    for (int k = 0; k < NCH; k++) {
        size_t o = (size_t)(bz * NCH + k) * (DINNER * 16) + rest;
        Hin[o] = hin;
        hin = fmaf(Wp[o], hin, Hloc[o]);
    }
}

// ---------------------------------------------------------------------------
extern "C" void kernel_launch(void* const* d_in, const int* in_sizes, int n_in,
                              void* d_out, int out_size, void* d_ws, size_t ws_size,
                              hipStream_t stream)
{
    const float* x        = (const float*)d_in[0];
    const float* in_nw    = (const float*)d_in[1];
    const float* in_nb    = (const float*)d_in[2];
    const float* ip_w     = (const float*)d_in[3];
    const float* ip_b     = (const float*)d_in[4];
    const float* f_in_w   = (const float*)d_in[5];
    const float* f_in_b   = (const float*)d_in[6];
    const float* f_conv_w = (const float*)d_in[7];
    const float* f_conv_b = (const float*)d_in[8];
    const float* f_xp_w   = (const float*)d_in[9];
    const float* f_dt_w   = (const float*)d_in[10];
    const float* f_dt_b   = (const float*)d_in[11];
    const float* f_A_log  = (const float*)d_in[12];
    const float* f_D      = (const float*)d_in[13];
    const float* f_out_w  = (const float*)d_in[14];
    const float* f_out_b  = (const float*)d_in[15];
    const float* b_in_w   = (const float*)d_in[16];
    const float* b_in_b   = (const float*)d_in[17];
    const float* b_conv_w = (const float*)d_in[18];
    const float* b_conv_b = (const float*)d_in[19];
    const float* b_xp_w   = (const float*)d_in[20];
    const float* b_dt_w   = (const float*)d_in[21];
    const float* b_dt_b   = (const float*)d_in[22];
    const float* b_A_log  = (const float*)d_in[23];
    const float* b_D      = (const float*)d_in[24];
    const float* b_out_w  = (const float*)d_in[25];
    const float* b_out_b  = (const float*)d_in[26];
    const float* op_w     = (const float*)d_in[27];
    const float* op_b     = (const float*)d_in[28];
    const float* norm_w   = (const float*)d_in[29];
    const float* norm_b   = (const float*)d_in[30];

    size_t off = 0;
    auto alloc = [&](size_t bytes) {
        void* p = (char*)d_ws + off;
        off += (bytes + 255) & ~(size_t)255;
        return p;
    };
    const size_t R = ROWS;
    ushort* xn_bf   = (ushort*)alloc(R * 768 * 2);
    ushort* xp_bf   = (ushort*)alloc(R * 768 * 2);
    ushort* xz_f_bf = (ushort*)alloc(R * 1536 * 2);
    ushort* xz_b_bf = (ushort*)alloc(R * 1536 * 2);
    ushort* xc_f_bf = (ushort*)alloc(R * 768 * 2);
    ushort* xc_b_bf = (ushort*)alloc(R * 768 * 2);
    float*  xd_f    = (float*)alloc(R * 56 * 4);
    float*  xd_b    = (float*)alloc(R * 56 * 4);
    float*  dt_f    = (float*)alloc(R * 768 * 4);
    float*  dt_b    = (float*)alloc(R * 768 * 4);
    ushort* y_f_bf  = (ushort*)alloc(R * 768 * 2);
    ushort* y_b_bf  = (ushort*)alloc(R * 768 * 2);
    ushort* cat_bf  = (ushort*)alloc(R * 768 * 2);
    float*  outraw  = (float*)alloc(R * 768 * 4);
    const size_t SCN = (size_t)4 * NCH * DINNER * 16;
    float* Hloc = (float*)alloc(SCN * 4);
    float* Wpb  = (float*)alloc(SCN * 4);
    float* Hin  = (float*)alloc(SCN * 4);
    ushort* Wt_ip   = (ushort*)alloc((size_t)768 * 768 * 2);
    ushort* Wt_fin  = (ushort*)alloc((size_t)1536 * 384 * 2);
    ushort* Wt_bin  = (ushort*)alloc((size_t)1536 * 384 * 2);
    ushort* Wt_fxp  = (ushort*)alloc((size_t)64 * 768 * 2);
    ushort* Wt_bxp  = (ushort*)alloc((size_t)64 * 768 * 2);
    ushort* Wt_fout = (ushort*)alloc((size_t)384 * 768 * 2);
    ushort* Wt_bout = (ushort*)alloc((size_t)384 * 768 * 2);
    ushort* Wt_op   = (ushort*)alloc((size_t)768 * 768 * 2);

    dim3 blk(256);

    // 0. transpose+cast all weights to bf16 W^T
    TDs td;
    int tile0 = 0, nd = 0;
    auto add = [&](const float* s, ushort* dst, int K, int N, int Np) {
        td.d[nd] = TD{s, dst, K, N, Np, tile0, K / 32};
        tile0 += (K / 32) * (Np / 32);
        nd++;
    };
    add(ip_w,    Wt_ip,   768, 768, 768);
    add(f_in_w,  Wt_fin,  384, 1536, 1536);
    add(b_in_w,  Wt_bin,  384, 1536, 1536);
    add(f_xp_w,  Wt_fxp,  768, 56, 64);
    add(b_xp_w,  Wt_bxp,  768, 56, 64);
    add(f_out_w, Wt_fout, 768, 384, 384);
    add(b_out_w, Wt_bout, 768, 384, 384);
    add(op_w,    Wt_op,   768, 768, 768);
    hipLaunchKernelGGL(tcast_kernel, dim3(tile0), blk, 0, stream, td);

    // 1. input layernorm -> bf16
    hipLaunchKernelGGL((ln_kernel<ushort>), dim3(ROWS), blk, 0, stream,
                       x, (const float*)nullptr, in_nw, in_nb, xn_bf);
    // 2. xp = xn @ ip_w + ip_b
    hipLaunchKernelGGL((mfma_gemm<128,64,true>), dim3(768/64, ROWS/128, 1), blk, 0, stream,
                       xn_bf, xn_bf, 768, Wt_ip, Wt_ip, 768, ip_b, ip_b,
                       (void*)xp_bf, (void*)xp_bf, 768, 768, 768);
    // 3. xz_{f,b} = split(xp) @ {f,b}_in_w + bias (fused, grid.z)
    hipLaunchKernelGGL((mfma_gemm<128,128,true>), dim3(1536/128, ROWS/128, 2), blk, 0, stream,
                       xp_bf, xp_bf + 384, 768, Wt_fin, Wt_bin, 384,
                       f_in_b, b_in_b, (void*)xz_f_bf, (void*)xz_b_bf, 1536, 1536, 384);
    // 4. conv + silu (f/b fused)
    hipLaunchKernelGGL(conv_silu_kernel, dim3(ROWS * DINNER / 256, 2), blk, 0, stream,
                       xz_f_bf, xz_b_bf, f_conv_w, f_conv_b, b_conv_w, b_conv_b,
                       xc_f_bf, xc_b_bf);
    // 5. xd_{f,b} = xc @ xp_w (fused, fp32 out, N=56 pad 64)
    hipLaunchKernelGGL((mfma_gemm<64,64,false>), dim3(1, ROWS/64, 2), blk, 0, stream,
                       xc_f_bf, xc_b_bf, 768, Wt_fxp, Wt_bxp, 768,
                       (const float*)nullptr, (const float*)nullptr,
                       (void*)xd_f, (void*)xd_b, 56, 56, 768);
    // 6. dt = softplus(xd[:, :24] @ dt_w + dt_b) (fused)
    hipLaunchKernelGGL(dt_gemm_kernel, dim3(768 / BN, ROWS / BM, 2), blk, 0, stream,
                       xd_f, xd_b, 56, f_dt_w, b_dt_w, 768, f_dt_b, b_dt_b,
                       dt_f, dt_b, 768, ROWS, 768, DTRANK);
    // 7. chunked selective scan
    hipLaunchKernelGGL((scan_chunk_kernel<false>), dim3(DINNER / 256, NCH, 4), blk, 0, stream,
                       dt_f, xc_f_bf, xd_f, xz_f_bf, f_A_log, f_D,
                       dt_b, xc_b_bf, xd_b, xz_b_bf, b_A_log, b_D,
                       Hloc, Wpb, (const float*)nullptr, (ushort*)nullptr, (ushort*)nullptr);
    hipLaunchKernelGGL(scan_combine, dim3(4 * DINNER * 16 / 256), blk, 0, stream,
                       Hloc, Wpb, Hin);
    hipLaunchKernelGGL((scan_chunk_kernel<true>), dim3(DINNER / 256, NCH, 4), blk, 0, stream,
                       dt_f, xc_f_bf, xd_f, xz_f_bf, f_A_log, f_D,
                       dt_b, xc_b_bf, xd_b, xz_b_bf, b_A_log, b_D,
                       (float*)nullptr, (float*)nullptr, Hin, y_f_bf, y_b_bf);
    // 8. out_{f,b} = y @ out_w + out_b -> concat (fused)
    hipLaunchKernelGGL((mfma_gemm<128,64,true>), dim3(384/64, ROWS/128, 2), blk, 0, stream,
                       y_f_bf, y_b_bf, 768, Wt_fout, Wt_bout, 768,
                       f_out_b, b_out_b, (void*)cat_bf, (void*)(cat_bf + 384), 768, 384, 768);
    // 9. op projection (fp32 out)
    hipLaunchKernelGGL((mfma_gemm<128,64,false>), dim3(768/64, ROWS/128, 1), blk, 0, stream,
                       cat_bf, cat_bf, 768, Wt_op, Wt_op, 768, op_b, op_b,
                       (void*)outraw, (void*)outraw, 768, 768, 768);
    // 10. final layernorm(residual + out) -> fp32 d_out
    hipLaunchKernelGGL((ln_kernel<float>), dim3(ROWS), blk, 0, stream,
                       x, outraw, norm_w, norm_b, (float*)d_out);
}